// Round 5
// baseline (132.358 us; speedup 1.0000x reference)
//
#include <hip/hip_runtime.h>
#include <hip/hip_bf16.h>
#include <math.h>

typedef __attribute__((ext_vector_type(4))) float f32x4;
typedef __attribute__((ext_vector_type(8))) short bf16x8;

#define N_TOK 8192
#define D_IN  1024
#define H_DIM 256
#define S_SPLIT 16
#define QSCALE 0.09016844f   // log2(e)/sqrt(256)

static __device__ __forceinline__ float bf2f(unsigned short u) {
  return __uint_as_float(((unsigned)u) << 16);
}
static __device__ __forceinline__ float fast_exp2(float x) {
  float e;
  asm("v_exp_f32 %0, %1" : "=v"(e) : "v"(x));
  return e;
}

// ---------------- prep: weight casts + wv2 = Wv^T @ w2, bv2 = bv . w2 ----------------
__global__ __launch_bounds__(256) void prep_kernel(
    const float* __restrict__ w1, const float* __restrict__ qw,
    const float* __restrict__ kw, const float* __restrict__ vw,
    const float* __restrict__ vb, const float* __restrict__ w2,
    __hip_bfloat16* __restrict__ w1b, __hip_bfloat16* __restrict__ qwb,
    __hip_bfloat16* __restrict__ kwb, float* __restrict__ wv2, float* __restrict__ bv2)
{
  int b = blockIdx.x, tid = threadIdx.x;
  if (b < 384) {
    const float* in; __hip_bfloat16* out; int base;
    if (b < 256)      { in = w1; out = w1b; base = b; }
    else if (b < 320) { in = qw; out = qwb; base = b - 256; }
    else              { in = kw; out = kwb; base = b - 320; }
    int i = base * 1024 + tid * 4;
    float4 v = *reinterpret_cast<const float4*>(in + i);
    union { __hip_bfloat16 h[4]; ushort4 u; } cv;
    cv.h[0] = __float2bfloat16(v.x);
    cv.h[1] = __float2bfloat16(v.y);
    cv.h[2] = __float2bfloat16(v.z);
    cv.h[3] = __float2bfloat16(v.w);
    *reinterpret_cast<ushort4*>(out + i) = cv.u;
    return;
  }
  // block 384: wv2[j] = sum_c vw[c][j] * w2[c]; bv2 = sum_c vb[c]*w2[c]
  __shared__ float sw2[256];
  __shared__ float red[256];
  sw2[tid] = w2[tid];
  __syncthreads();
  float a = 0.f;
  #pragma unroll 8
  for (int c = 0; c < 256; ++c) a += vw[c * 256 + tid] * sw2[c];
  wv2[tid] = a;
  red[tid] = vb[tid] * sw2[tid];
  __syncthreads();
  for (int s = 128; s > 0; s >>= 1) {
    if (tid < s) red[tid] += red[tid + s];
    __syncthreads();
  }
  if (tid == 0) bv2[0] = red[0];
}

// ---------------- fused front v2 ----------------
// 512 blocks x 16 rows, 512 threads (8 waves) -> 2 blocks/CU, 4 waves/SIMD.
// Phase 1: h = x@W1^T + b1 (reg-dbuf pipelined, fp32 x converted in-reg) -> swizzled LDS.
// Phase 2: q = (h Wq^T + bq)*QSCALE (waves 0-3), k = h Wk^T + bk (waves 4-7).
// Phase 3: hw2 = h.w2 + b2 (waves 0-3) ; vs = h.wv2 (waves 4-7).
__global__ __launch_bounds__(512, 2) void fused_front_kernel(
    const float* __restrict__ x,
    const __hip_bfloat16* __restrict__ W1,
    const __hip_bfloat16* __restrict__ Wq, const __hip_bfloat16* __restrict__ Wk,
    const float* __restrict__ b1, const float* __restrict__ bq, const float* __restrict__ bk,
    const float* __restrict__ w2, const float* __restrict__ wv2, const float* __restrict__ b2,
    __hip_bfloat16* __restrict__ Qo, __hip_bfloat16* __restrict__ Ko,
    float* __restrict__ hw2, float* __restrict__ vs)
{
  __shared__ __attribute__((aligned(16))) unsigned char h_lds[16 * 512];

  const int tid = threadIdx.x;
  const int w   = tid >> 6;
  const int l   = tid & 63;
  const int r16 = l & 15;
  const int kg  = l >> 4;
  const int rowbase = blockIdx.x * 16;

  // ---- phase 1: lin1, wave w owns cols w*32..w*32+31 ----
  {
    const int cb = w * 32;
    f32x4 acc[2];
    acc[0] = (f32x4){0.f, 0.f, 0.f, 0.f};
    acc[1] = (f32x4){0.f, 0.f, 0.f, 0.f};

    const float* xp = x + (size_t)(rowbase + r16) * D_IN + kg * 8;
    const __hip_bfloat16* wp = W1 + (size_t)(cb + r16) * D_IN + kg * 8;

    float4 xa[2][2];
    bf16x8 bw[2][2];
    xa[0][0] = *reinterpret_cast<const float4*>(xp);
    xa[0][1] = *reinterpret_cast<const float4*>(xp + 4);
    bw[0][0] = *reinterpret_cast<const bf16x8*>(wp);
    bw[0][1] = *reinterpret_cast<const bf16x8*>(wp + (size_t)16 * D_IN);

    #pragma unroll
    for (int s = 0; s < 32; ++s) {
      const int cur = s & 1, nxt = cur ^ 1;
      if (s + 1 < 32) {
        const int ko = (s + 1) * 32;
        xa[nxt][0] = *reinterpret_cast<const float4*>(xp + ko);
        xa[nxt][1] = *reinterpret_cast<const float4*>(xp + ko + 4);
        bw[nxt][0] = *reinterpret_cast<const bf16x8*>(wp + ko);
        bw[nxt][1] = *reinterpret_cast<const bf16x8*>(wp + (size_t)16 * D_IN + ko);
      }
      union { __hip_bfloat16 h[8]; bf16x8 v; } af;
      af.h[0] = __float2bfloat16(xa[cur][0].x);
      af.h[1] = __float2bfloat16(xa[cur][0].y);
      af.h[2] = __float2bfloat16(xa[cur][0].z);
      af.h[3] = __float2bfloat16(xa[cur][0].w);
      af.h[4] = __float2bfloat16(xa[cur][1].x);
      af.h[5] = __float2bfloat16(xa[cur][1].y);
      af.h[6] = __float2bfloat16(xa[cur][1].z);
      af.h[7] = __float2bfloat16(xa[cur][1].w);
      acc[0] = __builtin_amdgcn_mfma_f32_16x16x32_bf16(af.v, bw[cur][0], acc[0], 0, 0, 0);
      acc[1] = __builtin_amdgcn_mfma_f32_16x16x32_bf16(af.v, bw[cur][1], acc[1], 0, 0, 0);
    }

    // write h (with bias) to swizzled LDS [16 rows][512 B]
    #pragma unroll
    for (int c = 0; c < 2; ++c) {
      int col = cb + c * 16 + r16;
      float bs = b1[col];
      #pragma unroll
      for (int j = 0; j < 4; ++j) {
        int row = kg * 4 + j;
        int off = row * 512 + ((col * 2) ^ ((row & 7) << 4));
        *reinterpret_cast<__hip_bfloat16*>(&h_lds[0] + off) = __float2bfloat16(acc[c][j] + bs);
      }
    }
  }
  __syncthreads();

  // ---- phase 2: q (waves 0-3) / k (waves 4-7), each wave 16 rows x 64 cols ----
  {
    const bool isq = (w < 4);
    const __hip_bfloat16* Wp = isq ? Wq : Wk;
    const float* bp = isq ? bq : bk;
    __hip_bfloat16* Op = isq ? Qo : Ko;
    const float scl = isq ? QSCALE : 1.f;
    const int colb = (w & 3) * 64;

    // all 8 h fragments for this lane's row in registers
    const int rsw = (r16 & 7) << 4;
    bf16x8 afr[8];
    #pragma unroll
    for (int ks = 0; ks < 8; ++ks)
      afr[ks] = *reinterpret_cast<const bf16x8*>(
          &h_lds[0] + r16 * 512 + ((ks * 64 + kg * 16) ^ rsw));

    f32x4 acc[4];
    #pragma unroll
    for (int c = 0; c < 4; ++c) acc[c] = (f32x4){0.f, 0.f, 0.f, 0.f};

    const __hip_bfloat16* wqp = Wp + (size_t)(colb + r16) * H_DIM + kg * 8;

    bf16x8 wb[2][4];
    #pragma unroll
    for (int c = 0; c < 4; ++c)
      wb[0][c] = *reinterpret_cast<const bf16x8*>(wqp + (size_t)(c * 16) * H_DIM);

    #pragma unroll
    for (int ks = 0; ks < 8; ++ks) {
      const int cur = ks & 1, nxt = cur ^ 1;
      if (ks + 1 < 8) {
        #pragma unroll
        for (int c = 0; c < 4; ++c)
          wb[nxt][c] = *reinterpret_cast<const bf16x8*>(
              wqp + (size_t)(c * 16) * H_DIM + (ks + 1) * 32);
      }
      #pragma unroll
      for (int c = 0; c < 4; ++c)
        acc[c] = __builtin_amdgcn_mfma_f32_16x16x32_bf16(afr[ks], wb[cur][c], acc[c], 0, 0, 0);
    }

    #pragma unroll
    for (int c = 0; c < 4; ++c) {
      int col = colb + c * 16 + r16;
      float bb = bp[col];
      #pragma unroll
      for (int j = 0; j < 4; ++j) {
        int row = rowbase + kg * 4 + j;
        Op[(size_t)row * H_DIM + col] = __float2bfloat16((acc[c][j] + bb) * scl);
      }
    }
  }

  // ---- phase 3: rowdots from h_lds (no barrier: h_lds unchanged since phase-1 sync) ----
  {
    const bool isw2 = (w < 4);
    const float* wsel = isw2 ? w2 : wv2;
    const int row = (w & 3) * 4 + (l >> 4);
    const int c16 = l & 15;
    const int rsw = (row & 7) << 4;
    bf16x8 h0 = *reinterpret_cast<const bf16x8*>(&h_lds[0] + row * 512 + ((c16 * 32) ^ rsw));
    bf16x8 h1 = *reinterpret_cast<const bf16x8*>(&h_lds[0] + row * 512 + ((c16 * 32 + 16) ^ rsw));
    float s = 0.f;
    #pragma unroll
    for (int i = 0; i < 8; ++i) s += bf2f((unsigned short)h0[i]) * wsel[c16 * 16 + i];
    #pragma unroll
    for (int i = 0; i < 8; ++i) s += bf2f((unsigned short)h1[i]) * wsel[c16 * 16 + 8 + i];
    #pragma unroll
    for (int off = 1; off < 16; off <<= 1) s += __shfl_xor(s, off);
    if (c16 == 0) {
      if (isw2) hw2[rowbase + row] = s + b2[0];
      else      vs[rowbase + row]  = s;
    }
  }
}

// ---------------- attention partials (unchanged from R4) ----------------
#define KVBLK 32
#define KRANGE (N_TOK / S_SPLIT)   // 512 rows per split
__global__ __launch_bounds__(256, 2) void attn_partial_kernel(
    const __hip_bfloat16* __restrict__ Q, const __hip_bfloat16* __restrict__ K,
    const float* __restrict__ vsg, float* __restrict__ pden, float* __restrict__ pacc)
{
  __shared__ __attribute__((aligned(16))) unsigned char ktile[2][KVBLK * 512];
  __shared__ float vs_lds[KRANGE];

  const int tid = threadIdx.x;
  const int w   = tid >> 6;
  const int l   = tid & 63;
  const int r16 = l & 15;
  const int kg  = l >> 4;
  const int split   = blockIdx.y;
  const int mstart  = split * KRANGE;
  const int rowbase = blockIdx.x * 256 + w * 64;

  if (tid < KRANGE / 4)
    *reinterpret_cast<float4*>(vs_lds + tid * 4) =
        *reinterpret_cast<const float4*>(vsg + mstart + tid * 4);

  bf16x8 qf[4][8];
  #pragma unroll
  for (int sub = 0; sub < 4; ++sub) {
    const __hip_bfloat16* qp = Q + (size_t)(rowbase + sub * 16 + r16) * H_DIM + kg * 8;
    #pragma unroll
    for (int kk = 0; kk < 8; ++kk) qf[sub][kk] = *reinterpret_cast<const bf16x8*>(qp + kk * 32);
  }

  const int srow = tid >> 3;
  const int scb  = (tid & 7) * 64;
  const char* ksrc = (const char*)K + (size_t)(mstart + srow) * 512 + scb;
  const int ssw = (srow & 7) << 4;
  int sdst[4];
  #pragma unroll
  for (int i = 0; i < 4; ++i) sdst[i] = srow * 512 + ((scb + i * 16) ^ ssw);

  const int rsw = (r16 & 7) << 4;
  const int cb  = kg * 16;

  float den[4][4], acc[4][4];
  #pragma unroll
  for (int sub = 0; sub < 4; ++sub)
    #pragma unroll
    for (int j = 0; j < 4; ++j) { den[sub][j] = 0.f; acc[sub][j] = 0.f; }

  #pragma unroll
  for (int i = 0; i < 4; ++i)
    *reinterpret_cast<uint4*>(&ktile[0][0] + sdst[i]) =
        *reinterpret_cast<const uint4*>(ksrc + i * 16);
  __syncthreads();

  const int NT = KRANGE / KVBLK;   // 16
  for (int t = 0; t < NT; ++t) {
    const int cur = t & 1;
    const bool has = (t + 1 < NT);
    uint4 stg[4];
    if (has) {
      #pragma unroll
      for (int i = 0; i < 4; ++i)
        stg[i] = *reinterpret_cast<const uint4*>(ksrc + (size_t)(t + 1) * (KVBLK * 512) + i * 16);
    }
    float vsm0 = vs_lds[t * KVBLK + r16];
    float vsm1 = vs_lds[t * KVBLK + 16 + r16];

    f32x4 d[4][2];
    #pragma unroll
    for (int sub = 0; sub < 4; ++sub)
      #pragma unroll
      for (int n = 0; n < 2; ++n) d[sub][n] = (f32x4){0.f, 0.f, 0.f, 0.f};

    const unsigned char* kt = &ktile[cur][0];
    __builtin_amdgcn_s_setprio(1);
    #pragma unroll
    for (int n = 0; n < 2; ++n) {
      #pragma unroll
      for (int kk = 0; kk < 8; ++kk) {
        bf16x8 b = *reinterpret_cast<const bf16x8*>(kt + (n * 16 + r16) * 512 + ((kk * 64 + cb) ^ rsw));
        d[0][n] = __builtin_amdgcn_mfma_f32_16x16x32_bf16(qf[0][kk], b, d[0][n], 0, 0, 0);
        d[1][n] = __builtin_amdgcn_mfma_f32_16x16x32_bf16(qf[1][kk], b, d[1][n], 0, 0, 0);
        d[2][n] = __builtin_amdgcn_mfma_f32_16x16x32_bf16(qf[2][kk], b, d[2][n], 0, 0, 0);
        d[3][n] = __builtin_amdgcn_mfma_f32_16x16x32_bf16(qf[3][kk], b, d[3][n], 0, 0, 0);
      }
    }
    __builtin_amdgcn_s_setprio(0);

    #pragma unroll
    for (int sub = 0; sub < 4; ++sub)
      #pragma unroll
      for (int j = 0; j < 4; ++j) {
        float e0 = fast_exp2(d[sub][0][j]);
        float e1 = fast_exp2(d[sub][1][j]);
        den[sub][j] += e0 + e1;
        acc[sub][j] = fmaf(e0, vsm0, fmaf(e1, vsm1, acc[sub][j]));
      }

    if (has) {
      #pragma unroll
      for (int i = 0; i < 4; ++i)
        *reinterpret_cast<uint4*>(&ktile[cur ^ 1][0] + sdst[i]) = stg[i];
    }
    __syncthreads();
  }

  #pragma unroll
  for (int sub = 0; sub < 4; ++sub)
    #pragma unroll
    for (int j = 0; j < 4; ++j) {
      #pragma unroll
      for (int off = 1; off < 16; off <<= 1) {
        den[sub][j] += __shfl_xor(den[sub][j], off);
        acc[sub][j] += __shfl_xor(acc[sub][j], off);
      }
    }
  if (r16 == 0) {
    #pragma unroll
    for (int sub = 0; sub < 4; ++sub)
      #pragma unroll
      for (int j = 0; j < 4; ++j) {
        int row = rowbase + sub * 16 + kg * 4 + j;
        pden[split * N_TOK + row] = den[sub][j];
        pacc[split * N_TOK + row] = acc[sub][j];
      }
  }
}

// ---------------- merge splits + residual ----------------
__global__ __launch_bounds__(256) void combine_kernel(
    const float* __restrict__ pden, const float* __restrict__ pacc,
    const float* __restrict__ hw2, const float* __restrict__ bv2, float* __restrict__ out)
{
  int r = blockIdx.x * 256 + threadIdx.x;
  float den = 0.f, acc = 0.f;
  #pragma unroll
  for (int s = 0; s < S_SPLIT; ++s) {
    den += pden[s * N_TOK + r];
    acc += pacc[s * N_TOK + r];
  }
  out[r] = hw2[r] + acc / den + bv2[0];
}

extern "C" void kernel_launch(void* const* d_in, const int* in_sizes, int n_in,
                              void* d_out, int out_size, void* d_ws, size_t ws_size,
                              hipStream_t stream) {
  const float* x      = (const float*)d_in[0];
  const float* lin1_w = (const float*)d_in[1];
  const float* lin1_b = (const float*)d_in[2];
  const float* q_w    = (const float*)d_in[3];
  const float* q_b    = (const float*)d_in[4];
  const float* k_w    = (const float*)d_in[5];
  const float* k_b    = (const float*)d_in[6];
  const float* v_w    = (const float*)d_in[7];
  const float* v_b    = (const float*)d_in[8];
  const float* lin2_w = (const float*)d_in[9];
  const float* lin2_b = (const float*)d_in[10];
  float* out = (float*)d_out;

  char* ws = (char*)d_ws;
  size_t off = 0;
  auto alloc = [&](size_t bytes) {
    char* p = ws + off;
    off += (bytes + 255) & ~(size_t)255;
    return p;
  };
  __hip_bfloat16* w1b = (__hip_bfloat16*)alloc((size_t)H_DIM * D_IN * 2);
  __hip_bfloat16* qwb = (__hip_bfloat16*)alloc((size_t)H_DIM * H_DIM * 2);
  __hip_bfloat16* kwb = (__hip_bfloat16*)alloc((size_t)H_DIM * H_DIM * 2);
  __hip_bfloat16* qb  = (__hip_bfloat16*)alloc((size_t)N_TOK * H_DIM * 2);
  __hip_bfloat16* kb  = (__hip_bfloat16*)alloc((size_t)N_TOK * H_DIM * 2);
  float* hw2  = (float*)alloc((size_t)N_TOK * 4);
  float* vsv  = (float*)alloc((size_t)N_TOK * 4);
  float* wv2  = (float*)alloc((size_t)H_DIM * 4);
  float* bv2  = (float*)alloc(256);
  float* pden = (float*)alloc((size_t)S_SPLIT * N_TOK * 4);
  float* pacc = (float*)alloc((size_t)S_SPLIT * N_TOK * 4);
  (void)ws_size; (void)in_sizes; (void)n_in; (void)out_size;

  prep_kernel<<<385, 256, 0, stream>>>(lin1_w, q_w, k_w, v_w, v_b, lin2_w,
                                       w1b, qwb, kwb, wv2, bv2);

  fused_front_kernel<<<N_TOK / 16, 512, 0, stream>>>(
      x, w1b, qwb, kwb, lin1_b, q_b, k_b, lin2_w, wv2, lin2_b,
      qb, kb, hw2, vsv);

  attn_partial_kernel<<<dim3(32, S_SPLIT), 256, 0, stream>>>(qb, kb, vsv, pden, pacc);

  combine_kernel<<<N_TOK / 256, 256, 0, stream>>>(pden, pacc, hw2, bv2, out);
}

// Round 6
// 97.081 us; speedup vs baseline: 1.3634x; 1.3634x over previous
//
#include <hip/hip_runtime.h>
#include <hip/hip_bf16.h>
#include <math.h>

typedef __attribute__((ext_vector_type(4))) float f32x4;
typedef __attribute__((ext_vector_type(8))) short bf16x8;

#define N_TOK 8192
#define D_IN  1024
#define H_DIM 256
#define S_SPLIT 16
#define QSCALE 0.09016844f   // log2(e)/sqrt(256)

static __device__ __forceinline__ float bf2f(unsigned short u) {
  return __uint_as_float(((unsigned)u) << 16);
}
static __device__ __forceinline__ float fast_exp2(float x) {
  float e;
  asm("v_exp_f32 %0, %1" : "=v"(e) : "v"(x));
  return e;
}
static __device__ __forceinline__ void gload_lds16(const void* g, void* l) {
  __builtin_amdgcn_global_load_lds(
      (const __attribute__((address_space(1))) void*)g,
      (__attribute__((address_space(3))) void*)l, 16, 0, 0);
}

// ---------------- prep: weight casts + wv2 = Wv^T @ w2, bv2 = bv . w2 ----------------
__global__ __launch_bounds__(256) void prep_kernel(
    const float* __restrict__ w1, const float* __restrict__ qw,
    const float* __restrict__ kw, const float* __restrict__ vw,
    const float* __restrict__ vb, const float* __restrict__ w2,
    __hip_bfloat16* __restrict__ w1b, __hip_bfloat16* __restrict__ qwb,
    __hip_bfloat16* __restrict__ kwb, float* __restrict__ wv2, float* __restrict__ bv2)
{
  int b = blockIdx.x, tid = threadIdx.x;
  if (b < 384) {
    const float* in; __hip_bfloat16* out; int base;
    if (b < 256)      { in = w1; out = w1b; base = b; }
    else if (b < 320) { in = qw; out = qwb; base = b - 256; }
    else              { in = kw; out = kwb; base = b - 320; }
    int i = base * 1024 + tid * 4;
    float4 v = *reinterpret_cast<const float4*>(in + i);
    union { __hip_bfloat16 h[4]; ushort4 u; } cv;
    cv.h[0] = __float2bfloat16(v.x);
    cv.h[1] = __float2bfloat16(v.y);
    cv.h[2] = __float2bfloat16(v.z);
    cv.h[3] = __float2bfloat16(v.w);
    *reinterpret_cast<ushort4*>(out + i) = cv.u;
    return;
  }
  __shared__ float sw2[256];
  __shared__ float red[256];
  sw2[tid] = w2[tid];
  __syncthreads();
  float a = 0.f;
  #pragma unroll 8
  for (int c = 0; c < 256; ++c) a += vw[c * 256 + tid] * sw2[c];
  wv2[tid] = a;
  red[tid] = vb[tid] * sw2[tid];
  __syncthreads();
  for (int s = 128; s > 0; s >>= 1) {
    if (tid < s) red[tid] += red[tid + s];
    __syncthreads();
  }
  if (tid == 0) bv2[0] = red[0];
}

// ---------------- lin1: h = bf16(x @ W1^T + b1) ----------------
// grid 512 x 16 rows, 256 thr (4 waves; wave w -> cols w*64..+63).
// Per K-step (BK=64): W tile 32KB via global_load_lds (pre-swizzled source, linear
// dest, XOR-swizzled read); x tile -> regs -> cvt -> ds_write (write-late).
// One barrier per step; batched loads => per-tile (not per-load) latency.
#define L1_BK 64
__global__ __launch_bounds__(256, 2) void lin1_kernel(
    const float* __restrict__ x, const __hip_bfloat16* __restrict__ W1,
    const float* __restrict__ b1, __hip_bfloat16* __restrict__ Ho)
{
  // per buffer: A [16 rows][128B] @0 (2KB), W [256 cols][128B] @2048 (32KB)
  __shared__ __attribute__((aligned(16))) unsigned char lds[2][34816];
  const int tid = threadIdx.x;
  const int w = tid >> 6, l = tid & 63, r16 = l & 15, kg = l >> 4;
  const int rowbase = blockIdx.x * 16;
  const char* Wb = (const char*)W1;

  // x staging: thread t -> row t>>4, floats (t&15)*4..+3
  const int xrow = tid >> 4;
  const int xe   = (tid & 15) * 4;
  const float* xsrc = x + (size_t)(rowbase + xrow) * D_IN + xe;
  const int xdst = xrow * 128 + ((xe * 2) ^ ((xrow & 7) << 4));

  f32x4 acc[4];
  #pragma unroll
  for (int c = 0; c < 4; ++c) acc[c] = (f32x4){0.f, 0.f, 0.f, 0.f};

  // prologue: stage tile 0
  {
    f32x4 xv = *reinterpret_cast<const f32x4*>(xsrc);
    #pragma unroll
    for (int i = 0; i < 8; ++i) {
      int p = i * 4096 + tid * 16;
      int col = p >> 7, bb = p & 127;
      gload_lds16(Wb + (size_t)col * 2048 + (bb ^ ((col & 7) << 4)), &lds[0][2048 + p]);
    }
    union { __hip_bfloat16 h[4]; ushort4 u; } cv;
    cv.h[0] = __float2bfloat16(xv[0]); cv.h[1] = __float2bfloat16(xv[1]);
    cv.h[2] = __float2bfloat16(xv[2]); cv.h[3] = __float2bfloat16(xv[3]);
    *reinterpret_cast<ushort4*>(&lds[0][xdst]) = cv.u;
  }
  __syncthreads();

  const int rsw = (r16 & 7) << 4;
  for (int t = 0; t < 16; ++t) {
    const int cur = t & 1;
    f32x4 xv;
    if (t + 1 < 16) {
      xv = *reinterpret_cast<const f32x4*>(xsrc + (t + 1) * L1_BK);
      const int k0b = (t + 1) * L1_BK * 2;
      #pragma unroll
      for (int i = 0; i < 8; ++i) {
        int p = i * 4096 + tid * 16;
        int col = p >> 7, bb = p & 127;
        gload_lds16(Wb + (size_t)col * 2048 + k0b + (bb ^ ((col & 7) << 4)),
                    &lds[cur ^ 1][2048 + p]);
      }
    }
    const unsigned char* A = &lds[cur][0];
    const unsigned char* W = &lds[cur][2048];
    #pragma unroll
    for (int ks = 0; ks < 2; ++ks) {
      bf16x8 a = *reinterpret_cast<const bf16x8*>(A + r16 * 128 + ((ks * 64 + kg * 16) ^ rsw));
      #pragma unroll
      for (int c = 0; c < 4; ++c) {
        const int col = w * 64 + c * 16 + r16;   // col&7 == r16&7
        bf16x8 b = *reinterpret_cast<const bf16x8*>(W + col * 128 + ((ks * 64 + kg * 16) ^ rsw));
        acc[c] = __builtin_amdgcn_mfma_f32_16x16x32_bf16(a, b, acc[c], 0, 0, 0);
      }
    }
    if (t + 1 < 16) {
      union { __hip_bfloat16 h[4]; ushort4 u; } cv;
      cv.h[0] = __float2bfloat16(xv[0]); cv.h[1] = __float2bfloat16(xv[1]);
      cv.h[2] = __float2bfloat16(xv[2]); cv.h[3] = __float2bfloat16(xv[3]);
      *reinterpret_cast<ushort4*>(&lds[cur ^ 1][xdst]) = cv.u;
    }
    __syncthreads();
  }

  // epilogue: h+bias -> LDS [16][512B] linear, then coalesced 32B/thread stores
  #pragma unroll
  for (int c = 0; c < 4; ++c) {
    int col = w * 64 + c * 16 + r16;
    float bs = b1[col];
    #pragma unroll
    for (int j = 0; j < 4; ++j)
      *reinterpret_cast<__hip_bfloat16*>(&lds[0][(kg * 4 + j) * 512 + col * 2]) =
          __float2bfloat16(acc[c][j] + bs);
  }
  __syncthreads();
  {
    int row = tid >> 4, byteo = (tid & 15) * 32;
    uint4 v0 = *reinterpret_cast<uint4*>(&lds[0][row * 512 + byteo]);
    uint4 v1 = *reinterpret_cast<uint4*>(&lds[0][row * 512 + byteo + 16]);
    char* dst = (char*)Ho + (size_t)(rowbase + row) * 512 + byteo;
    *reinterpret_cast<uint4*>(dst) = v0;
    *reinterpret_cast<uint4*>(dst + 16) = v1;
  }
}

// ---------------- qk: q = (h Wq^T + bq)*QSCALE, k = h Wk^T + bk, + rowdots ----------------
// grid 512 x 16 rows, 512 thr (8 waves: 0-3 q, 4-7 k; wave -> 64 cols).
// All 32 W-fragments batch-loaded to regs (one MLP burst); h tile via one
// global_load_lds call (swizzled source). 32 MFMA with no per-MFMA mem waits.
__global__ __launch_bounds__(512, 2) void qk_kernel(
    const __hip_bfloat16* __restrict__ Hi,
    const __hip_bfloat16* __restrict__ Wq, const __hip_bfloat16* __restrict__ Wk,
    const float* __restrict__ bq, const float* __restrict__ bk,
    const float* __restrict__ w2, const float* __restrict__ wv2, const float* __restrict__ b2,
    __hip_bfloat16* __restrict__ Qo, __hip_bfloat16* __restrict__ Ko,
    float* __restrict__ hw2, float* __restrict__ vs)
{
  __shared__ __attribute__((aligned(16))) unsigned char lds[8192 + 16384];
  const int tid = threadIdx.x;
  const int w = tid >> 6, l = tid & 63, r16 = l & 15, kg = l >> 4;
  const int rowbase = blockIdx.x * 16;
  const bool isq = (w < 4);
  const int cb = (w & 3) * 64;

  // batch-issue all W fragment loads
  const __hip_bfloat16* Wp = isq ? Wq : Wk;
  bf16x8 bfr[8][4];
  #pragma unroll
  for (int ks = 0; ks < 8; ++ks)
    #pragma unroll
    for (int c = 0; c < 4; ++c)
      bfr[ks][c] = *reinterpret_cast<const bf16x8*>(
          Wp + (size_t)(cb + c * 16 + r16) * H_DIM + ks * 32 + kg * 8);

  // stage h tile (8KB, one call, pre-swizzled source)
  {
    int p = tid * 16;
    int row = p >> 9, bb = p & 511;
    gload_lds16((const char*)Hi + (size_t)(rowbase + row) * 512 + (bb ^ ((row & 7) << 4)),
                &lds[p]);
  }
  __syncthreads();

  const int rsw = (r16 & 7) << 4;
  bf16x8 afr[8];
  #pragma unroll
  for (int ks = 0; ks < 8; ++ks)
    afr[ks] = *reinterpret_cast<const bf16x8*>(&lds[0] + r16 * 512 + ((ks * 64 + kg * 16) ^ rsw));

  f32x4 acc[4];
  #pragma unroll
  for (int c = 0; c < 4; ++c) acc[c] = (f32x4){0.f, 0.f, 0.f, 0.f};
  #pragma unroll
  for (int ks = 0; ks < 8; ++ks)
    #pragma unroll
    for (int c = 0; c < 4; ++c)
      acc[c] = __builtin_amdgcn_mfma_f32_16x16x32_bf16(afr[ks], bfr[ks][c], acc[c], 0, 0, 0);

  // epilogue: bias (+scale) -> LDS out area, coalesced stores
  const float* bp = isq ? bq : bk;
  const float scl = isq ? QSCALE : 1.f;
  unsigned char* outa = &lds[8192 + (isq ? 0 : 8192)];
  #pragma unroll
  for (int c = 0; c < 4; ++c) {
    int col = cb + c * 16 + r16;
    float bb = bp[col];
    #pragma unroll
    for (int j = 0; j < 4; ++j)
      *reinterpret_cast<__hip_bfloat16*>(outa + (kg * 4 + j) * 512 + col * 2) =
          __float2bfloat16((acc[c][j] + bb) * scl);
  }
  __syncthreads();
  {
    int g = tid >> 8, tt = tid & 255;
    int row = tt >> 4, byteo = (tt & 15) * 32;
    const unsigned char* sa = &lds[8192 + g * 8192 + row * 512 + byteo];
    uint4 v0 = *reinterpret_cast<const uint4*>(sa);
    uint4 v1 = *reinterpret_cast<const uint4*>(sa + 16);
    char* dst = (char*)(g ? Ko : Qo) + (size_t)(rowbase + row) * 512 + byteo;
    *reinterpret_cast<uint4*>(dst) = v0;
    *reinterpret_cast<uint4*>(dst + 16) = v1;
  }
  // rowdots from resident h tile: waves 0-3 -> hw2 (w2), waves 4-7 -> vs (wv2)
  {
    const float* wsel = isq ? w2 : wv2;
    int row = (w & 3) * 4 + (l >> 4);
    int c16 = l & 15;
    int rs2 = (row & 7) << 4;
    bf16x8 h0 = *reinterpret_cast<const bf16x8*>(&lds[0] + row * 512 + ((c16 * 32) ^ rs2));
    bf16x8 h1 = *reinterpret_cast<const bf16x8*>(&lds[0] + row * 512 + ((c16 * 32 + 16) ^ rs2));
    float s = 0.f;
    #pragma unroll
    for (int i = 0; i < 8; ++i) s += bf2f((unsigned short)h0[i]) * wsel[c16 * 16 + i];
    #pragma unroll
    for (int i = 0; i < 8; ++i) s += bf2f((unsigned short)h1[i]) * wsel[c16 * 16 + 8 + i];
    #pragma unroll
    for (int off = 1; off < 16; off <<= 1) s += __shfl_xor(s, off);
    if (c16 == 0) {
      if (isq) hw2[rowbase + row] = s + b2[0];
      else     vs[rowbase + row]  = s;
    }
  }
}

// ---------------- attention partials (unchanged, validated) ----------------
#define KVBLK 32
#define KRANGE (N_TOK / S_SPLIT)   // 512 rows per split
__global__ __launch_bounds__(256, 2) void attn_partial_kernel(
    const __hip_bfloat16* __restrict__ Q, const __hip_bfloat16* __restrict__ K,
    const float* __restrict__ vsg, float* __restrict__ pden, float* __restrict__ pacc)
{
  __shared__ __attribute__((aligned(16))) unsigned char ktile[2][KVBLK * 512];
  __shared__ float vs_lds[KRANGE];

  const int tid = threadIdx.x;
  const int w   = tid >> 6;
  const int l   = tid & 63;
  const int r16 = l & 15;
  const int kg  = l >> 4;
  const int split   = blockIdx.y;
  const int mstart  = split * KRANGE;
  const int rowbase = blockIdx.x * 256 + w * 64;

  if (tid < KRANGE / 4)
    *reinterpret_cast<float4*>(vs_lds + tid * 4) =
        *reinterpret_cast<const float4*>(vsg + mstart + tid * 4);

  bf16x8 qf[4][8];
  #pragma unroll
  for (int sub = 0; sub < 4; ++sub) {
    const __hip_bfloat16* qp = Q + (size_t)(rowbase + sub * 16 + r16) * H_DIM + kg * 8;
    #pragma unroll
    for (int kk = 0; kk < 8; ++kk) qf[sub][kk] = *reinterpret_cast<const bf16x8*>(qp + kk * 32);
  }

  const int srow = tid >> 3;
  const int scb  = (tid & 7) * 64;
  const char* ksrc = (const char*)K + (size_t)(mstart + srow) * 512 + scb;
  const int ssw = (srow & 7) << 4;
  int sdst[4];
  #pragma unroll
  for (int i = 0; i < 4; ++i) sdst[i] = srow * 512 + ((scb + i * 16) ^ ssw);

  const int rsw = (r16 & 7) << 4;
  const int cb  = kg * 16;

  float den[4][4], acc[4][4];
  #pragma unroll
  for (int sub = 0; sub < 4; ++sub)
    #pragma unroll
    for (int j = 0; j < 4; ++j) { den[sub][j] = 0.f; acc[sub][j] = 0.f; }

  #pragma unroll
  for (int i = 0; i < 4; ++i)
    *reinterpret_cast<uint4*>(&ktile[0][0] + sdst[i]) =
        *reinterpret_cast<const uint4*>(ksrc + i * 16);
  __syncthreads();

  const int NT = KRANGE / KVBLK;   // 16
  for (int t = 0; t < NT; ++t) {
    const int cur = t & 1;
    const bool has = (t + 1 < NT);
    uint4 stg[4];
    if (has) {
      #pragma unroll
      for (int i = 0; i < 4; ++i)
        stg[i] = *reinterpret_cast<const uint4*>(ksrc + (size_t)(t + 1) * (KVBLK * 512) + i * 16);
    }
    float vsm0 = vs_lds[t * KVBLK + r16];
    float vsm1 = vs_lds[t * KVBLK + 16 + r16];

    f32x4 d[4][2];
    #pragma unroll
    for (int sub = 0; sub < 4; ++sub)
      #pragma unroll
      for (int n = 0; n < 2; ++n) d[sub][n] = (f32x4){0.f, 0.f, 0.f, 0.f};

    const unsigned char* kt = &ktile[cur][0];
    __builtin_amdgcn_s_setprio(1);
    #pragma unroll
    for (int n = 0; n < 2; ++n) {
      #pragma unroll
      for (int kk = 0; kk < 8; ++kk) {
        bf16x8 b = *reinterpret_cast<const bf16x8*>(kt + (n * 16 + r16) * 512 + ((kk * 64 + cb) ^ rsw));
        d[0][n] = __builtin_amdgcn_mfma_f32_16x16x32_bf16(qf[0][kk], b, d[0][n], 0, 0, 0);
        d[1][n] = __builtin_amdgcn_mfma_f32_16x16x32_bf16(qf[1][kk], b, d[1][n], 0, 0, 0);
        d[2][n] = __builtin_amdgcn_mfma_f32_16x16x32_bf16(qf[2][kk], b, d[2][n], 0, 0, 0);
        d[3][n] = __builtin_amdgcn_mfma_f32_16x16x32_bf16(qf[3][kk], b, d[3][n], 0, 0, 0);
      }
    }
    __builtin_amdgcn_s_setprio(0);

    #pragma unroll
    for (int sub = 0; sub < 4; ++sub)
      #pragma unroll
      for (int j = 0; j < 4; ++j) {
        float e0 = fast_exp2(d[sub][0][j]);
        float e1 = fast_exp2(d[sub][1][j]);
        den[sub][j] += e0 + e1;
        acc[sub][j] = fmaf(e0, vsm0, fmaf(e1, vsm1, acc[sub][j]));
      }

    if (has) {
      #pragma unroll
      for (int i = 0; i < 4; ++i)
        *reinterpret_cast<uint4*>(&ktile[cur ^ 1][0] + sdst[i]) = stg[i];
    }
    __syncthreads();
  }

  #pragma unroll
  for (int sub = 0; sub < 4; ++sub)
    #pragma unroll
    for (int j = 0; j < 4; ++j) {
      #pragma unroll
      for (int off = 1; off < 16; off <<= 1) {
        den[sub][j] += __shfl_xor(den[sub][j], off);
        acc[sub][j] += __shfl_xor(acc[sub][j], off);
      }
    }
  if (r16 == 0) {
    #pragma unroll
    for (int sub = 0; sub < 4; ++sub)
      #pragma unroll
      for (int j = 0; j < 4; ++j) {
        int row = rowbase + sub * 16 + kg * 4 + j;
        pden[split * N_TOK + row] = den[sub][j];
        pacc[split * N_TOK + row] = acc[sub][j];
      }
  }
}

// ---------------- merge splits + residual ----------------
__global__ __launch_bounds__(256) void combine_kernel(
    const float* __restrict__ pden, const float* __restrict__ pacc,
    const float* __restrict__ hw2, const float* __restrict__ bv2, float* __restrict__ out)
{
  int r = blockIdx.x * 256 + threadIdx.x;
  float den = 0.f, acc = 0.f;
  #pragma unroll
  for (int s = 0; s < S_SPLIT; ++s) {
    den += pden[s * N_TOK + r];
    acc += pacc[s * N_TOK + r];
  }
  out[r] = hw2[r] + acc / den + bv2[0];
}

extern "C" void kernel_launch(void* const* d_in, const int* in_sizes, int n_in,
                              void* d_out, int out_size, void* d_ws, size_t ws_size,
                              hipStream_t stream) {
  const float* x      = (const float*)d_in[0];
  const float* lin1_w = (const float*)d_in[1];
  const float* lin1_b = (const float*)d_in[2];
  const float* q_w    = (const float*)d_in[3];
  const float* q_b    = (const float*)d_in[4];
  const float* k_w    = (const float*)d_in[5];
  const float* k_b    = (const float*)d_in[6];
  const float* v_w    = (const float*)d_in[7];
  const float* v_b    = (const float*)d_in[8];
  const float* lin2_w = (const float*)d_in[9];
  const float* lin2_b = (const float*)d_in[10];
  float* out = (float*)d_out;

  char* ws = (char*)d_ws;
  size_t off = 0;
  auto alloc = [&](size_t bytes) {
    char* p = ws + off;
    off += (bytes + 255) & ~(size_t)255;
    return p;
  };
  __hip_bfloat16* w1b = (__hip_bfloat16*)alloc((size_t)H_DIM * D_IN * 2);
  __hip_bfloat16* qwb = (__hip_bfloat16*)alloc((size_t)H_DIM * H_DIM * 2);
  __hip_bfloat16* kwb = (__hip_bfloat16*)alloc((size_t)H_DIM * H_DIM * 2);
  __hip_bfloat16* hb  = (__hip_bfloat16*)alloc((size_t)N_TOK * H_DIM * 2);
  __hip_bfloat16* qb  = (__hip_bfloat16*)alloc((size_t)N_TOK * H_DIM * 2);
  __hip_bfloat16* kb  = (__hip_bfloat16*)alloc((size_t)N_TOK * H_DIM * 2);
  float* hw2  = (float*)alloc((size_t)N_TOK * 4);
  float* vsv  = (float*)alloc((size_t)N_TOK * 4);
  float* wv2  = (float*)alloc((size_t)H_DIM * 4);
  float* bv2  = (float*)alloc(256);
  float* pden = (float*)alloc((size_t)S_SPLIT * N_TOK * 4);
  float* pacc = (float*)alloc((size_t)S_SPLIT * N_TOK * 4);
  (void)ws_size; (void)in_sizes; (void)n_in; (void)out_size;

  prep_kernel<<<385, 256, 0, stream>>>(lin1_w, q_w, k_w, v_w, v_b, lin2_w,
                                       w1b, qwb, kwb, wv2, bv2);

  lin1_kernel<<<N_TOK / 16, 256, 0, stream>>>(x, w1b, lin1_b, hb);

  qk_kernel<<<N_TOK / 16, 512, 0, stream>>>(hb, qwb, kwb, q_b, k_b,
                                            lin2_w, wv2, lin2_b, qb, kb, hw2, vsv);

  attn_partial_kernel<<<dim3(32, S_SPLIT), 256, 0, stream>>>(qb, kb, vsv, pden, pacc);

  combine_kernel<<<N_TOK / 256, 256, 0, stream>>>(pden, pacc, hw2, bv2, out);
}